// Round 1
// baseline (4543.484 us; speedup 1.0000x reference)
//
#include <hip/hip_runtime.h>
#include <math.h>

// Problem constants (fixed by the reference setup)
#define B_SZ   64
#define C_SZ   12
#define T_SZ   2048
#define K_SZ   2048
#define LMAX   11
#define CMAX   11     // C-1
#define PL_PAD 1024
#define A_PARAM 7.0f

#define BLOCK  256
#define BG     4               // batch groups per kernel
#define BPG    (B_SZ / BG)     // 16 batches per block

__global__ __launch_bounds__(BLOCK) void rocket_kernel(
    const float* __restrict__ x,        // (B, C, T)
    const float* __restrict__ weights,  // (K, CMAX, LMAX)
    const float* __restrict__ biases,   // (K,)
    const int*   __restrict__ ch_idx,   // (K, CMAX)
    const int*   __restrict__ dils,     // (K,)
    const int*   __restrict__ offs,     // (K,)
    const int*   __restrict__ olens,    // (K,)
    float*       __restrict__ out)      // (B, 2K)
{
    __shared__ float sW[CMAX][LMAX];
    __shared__ int   sCh[CMAX];
    __shared__ int   sMeta[2];          // n (channels), L (taps)
    __shared__ float sRed[2][4];        // cross-wave reduction (4 waves)

    const int k   = blockIdx.x;
    const int tid = threadIdx.x;

    if (tid < CMAX * LMAX)
        sW[tid / LMAX][tid % LMAX] = weights[(size_t)k * (CMAX * LMAX) + tid];
    if (tid < CMAX)
        sCh[tid] = ch_idx[(size_t)k * CMAX + tid];
    __syncthreads();

    if (tid == 0) {
        // Effective channel count n and tap count L: rows/taps beyond them are
        // exactly zero by construction; skipping zero weights changes nothing.
        int n = 0, L = 0;
        for (int c = 0; c < CMAX; ++c) {
            bool nz = false;
            for (int l = 0; l < LMAX; ++l) {
                if (sW[c][l] != 0.0f) { nz = true; if (l + 1 > L) L = l + 1; }
            }
            if (nz) n = c + 1;
        }
        sMeta[0] = n; sMeta[1] = L;
    }
    __syncthreads();

    const int   n    = sMeta[0];
    const int   L    = sMeta[1];
    const int   d    = dils[k];
    const int   off  = offs[k] - PL_PAD;   // index into real x (may be negative)
    const int   olen = olens[k];
    const float bias = biases[k];
    const float inv_olen = 1.0f / (float)olen;

    const int b0   = blockIdx.y * BPG;
    const int lane = tid & 63;
    const int wid  = tid >> 6;

    for (int b = b0; b < b0 + BPG; ++b) {
        float psum = 0.0f;
        float pmax = -INFINITY;

        for (int tt = 0; tt < T_SZ / BLOCK; ++tt) {
            const int t = tt * BLOCK + tid;
            float y = bias;
            const int pos0 = off + t;
            for (int c = 0; c < n; ++c) {
                const float* xb = x + ((size_t)b * C_SZ + sCh[c]) * T_SZ;
                int pos = pos0;
                #pragma unroll 1
                for (int l = 0; l < L; ++l) {
                    const float xv = ((unsigned)pos < (unsigned)T_SZ) ? xb[pos] : 0.0f;
                    y = fmaf(sW[c][l], xv, y);
                    pos += d;
                }
            }
            if (t < olen) {
                psum += 1.0f / (1.0f + __expf(3.0f - A_PARAM * y));
                pmax = fmaxf(pmax, y);
            }
        }

        // wave reduction (64-wide)
        for (int o = 32; o > 0; o >>= 1) {
            psum += __shfl_down(psum, o, 64);
            pmax  = fmaxf(pmax, __shfl_down(pmax, o, 64));
        }
        if (lane == 0) { sRed[0][wid] = psum; sRed[1][wid] = pmax; }
        __syncthreads();
        if (tid == 0) {
            const float s = sRed[0][0] + sRed[0][1] + sRed[0][2] + sRed[0][3];
            const float m = fmaxf(fmaxf(sRed[1][0], sRed[1][1]),
                                  fmaxf(sRed[1][2], sRed[1][3]));
            out[(size_t)b * (2 * K_SZ) + 2 * k]     = s * inv_olen;
            out[(size_t)b * (2 * K_SZ) + 2 * k + 1] = m;
        }
        __syncthreads();   // protect sRed before next b
    }
}

extern "C" void kernel_launch(void* const* d_in, const int* in_sizes, int n_in,
                              void* d_out, int out_size, void* d_ws, size_t ws_size,
                              hipStream_t stream) {
    const float* x       = (const float*)d_in[0];
    const float* weights = (const float*)d_in[1];
    const float* biases  = (const float*)d_in[2];
    const int*   ch_idx  = (const int*)  d_in[3];
    const int*   dils    = (const int*)  d_in[4];
    const int*   offs    = (const int*)  d_in[5];
    const int*   olens   = (const int*)  d_in[6];
    float*       out     = (float*)d_out;

    dim3 grid(K_SZ, BG);
    rocket_kernel<<<grid, BLOCK, 0, stream>>>(x, weights, biases, ch_idx,
                                              dils, offs, olens, out);
}

// Round 2
// 3078.111 us; speedup vs baseline: 1.4761x; 1.4761x over previous
//
#include <hip/hip_runtime.h>
#include <math.h>

// Problem constants (fixed by the reference setup)
#define B_SZ   64
#define C_SZ   12
#define T_SZ   2048
#define K_SZ   2048
#define LMAX   11
#define CMAX   11     // C-1
#define PL_PAD 1024
#define XP     8192   // padded row length in ws: covers worst-case tail gather (7844)
#define A_PARAM 7.0f

#define BLOCK  256
#define BG     4               // batch groups per kernel
#define BPG    (B_SZ / BG)     // 16 batches per block
#define R      8               // outputs per thread (dilation-strided register tile)

// ---------------------------------------------------------------------------
// Fill xpad(B, C, XP) with left pad PL_PAD of zeros, x in [PL_PAD, PL_PAD+T),
// zeros after. PL_PAD and T are multiples of 4 so float4 chunks never straddle.
__global__ __launch_bounds__(256) void pad_kernel(const float* __restrict__ x,
                                                  float* __restrict__ xpad) {
    const int ROW4 = XP / 4;
    const int u = blockIdx.x * 256 + threadIdx.x;       // float4 index
    const int p4 = u % ROW4;
    const int bc = u / ROW4;
    const int p  = p4 * 4;
    float4 val = make_float4(0.f, 0.f, 0.f, 0.f);
    if (p >= PL_PAD && p < PL_PAD + T_SZ)
        val = *(const float4*)(x + (size_t)bc * T_SZ + (p - PL_PAD));
    ((float4*)xpad)[u] = val;
}

// ---------------------------------------------------------------------------
template<int LC, bool PAD>
__device__ __forceinline__ void do_item(
    const float* __restrict__ xb,        // batch base: xsrc + b*C*stride
    const int*   __restrict__ sCh,
    const float  (* __restrict__ sW)[LMAX],
    int n, int d, int off_eff, int q, int j0, int olen, float bias,
    float& psum, float& pmax)
{
    constexpr int NV = R + LC - 1;
    float y[R];
    #pragma unroll
    for (int r = 0; r < R; ++r) y[r] = bias;

    const int base0 = off_eff + q + j0 * d;   // position of v[0] within row
    for (int c = 0; c < n; ++c) {
        const float* row = xb + (size_t)sCh[c] * (PAD ? XP : T_SZ);
        float v[NV];
        #pragma unroll
        for (int i = 0; i < NV; ++i) {
            const int pos = base0 + i * d;
            if (PAD) {
                v[i] = row[pos];
            } else {
                v[i] = ((unsigned)pos < (unsigned)T_SZ) ? row[pos] : 0.0f;
            }
        }
        #pragma unroll
        for (int l = 0; l < LC; ++l) {
            const float wl = sW[c][l];
            #pragma unroll
            for (int r2 = 0; r2 < R; ++r2)
                y[r2] = fmaf(wl, v[l + r2], y[r2]);
        }
    }
    #pragma unroll
    for (int r = 0; r < R; ++r) {
        const int t = q + (j0 + r) * d;
        if (t < olen) {
            psum += 1.0f / (1.0f + __expf(3.0f - A_PARAM * y[r]));
            pmax  = fmaxf(pmax, y[r]);
        }
    }
}

template<int LC, bool PAD>
__device__ __forceinline__ void run_all(
    const float* __restrict__ xsrc, float* __restrict__ out,
    const int* __restrict__ sCh, const float (* __restrict__ sW)[LMAX],
    float (* __restrict__ sRed)[4],
    int n, int d, int off_eff, int olen, float bias, int k, int b0)
{
    const int tid  = threadIdx.x;
    const int lane = tid & 63;
    const int wid  = tid >> 6;
    const float inv_olen = 1.0f / (float)olen;

    const int nj    = (T_SZ + d - 1) / d;
    const int njblk = (nj + R - 1) / R;
    const int nwork = d * njblk;

    for (int b = b0; b < b0 + BPG; ++b) {
        float psum = 0.0f;
        float pmax = -INFINITY;
        const float* xb = xsrc + (size_t)b * C_SZ * (PAD ? XP : T_SZ);

        for (int w = tid; w < nwork; w += BLOCK) {
            const int q  = w % d;
            const int j0 = (w / d) * R;
            if (q + j0 * d < T_SZ)   // item with at least one in-range output
                do_item<LC, PAD>(xb, sCh, sW, n, d, off_eff, q, j0, olen, bias,
                                 psum, pmax);
        }

        // wave reduction (64-wide), then cross-wave via LDS
        for (int o = 32; o > 0; o >>= 1) {
            psum += __shfl_down(psum, o, 64);
            pmax  = fmaxf(pmax, __shfl_down(pmax, o, 64));
        }
        if (lane == 0) { sRed[0][wid] = psum; sRed[1][wid] = pmax; }
        __syncthreads();
        if (tid == 0) {
            const float s = sRed[0][0] + sRed[0][1] + sRed[0][2] + sRed[0][3];
            const float m = fmaxf(fmaxf(sRed[1][0], sRed[1][1]),
                                  fmaxf(sRed[1][2], sRed[1][3]));
            out[(size_t)b * (2 * K_SZ) + 2 * k]     = s * inv_olen;
            out[(size_t)b * (2 * K_SZ) + 2 * k + 1] = m;
        }
        __syncthreads();
    }
}

template<bool PAD>
__global__ __launch_bounds__(BLOCK) void rocket_main(
    const float* __restrict__ xsrc,     // xpad if PAD else x
    const float* __restrict__ weights,  // (K, CMAX, LMAX)
    const float* __restrict__ biases,   // (K,)
    const int*   __restrict__ ch_idx,   // (K, CMAX)
    const int*   __restrict__ dils,     // (K,)
    const int*   __restrict__ offs,     // (K,)
    const int*   __restrict__ olens,    // (K,)
    float*       __restrict__ out)      // (B, 2K)
{
    __shared__ float sW[CMAX][LMAX];
    __shared__ int   sCh[CMAX];
    __shared__ int   sMeta[2];
    __shared__ float sRed[2][4];

    const int k   = blockIdx.x;
    const int tid = threadIdx.x;

    if (tid < CMAX * LMAX)
        sW[tid / LMAX][tid % LMAX] = weights[(size_t)k * (CMAX * LMAX) + tid];
    if (tid < CMAX)
        sCh[tid] = ch_idx[(size_t)k * CMAX + tid];
    __syncthreads();

    if (tid == 0) {
        // Effective channel count n and tap count L (zero rows/taps contribute
        // nothing; weights are standard normal so exact zeros only at padding).
        int n = 0, L = 0;
        for (int c = 0; c < CMAX; ++c) {
            bool nz = false;
            for (int l = 0; l < LMAX; ++l) {
                if (sW[c][l] != 0.0f) { nz = true; if (l + 1 > L) L = l + 1; }
            }
            if (nz) n = c + 1;
        }
        sMeta[0] = n; sMeta[1] = L;
    }
    __syncthreads();

    const int   n    = sMeta[0];
    const int   L    = sMeta[1];
    const int   d    = dils[k];
    const int   off_eff = PAD ? offs[k] : (offs[k] - PL_PAD);
    const int   olen = olens[k];
    const float bias = biases[k];
    const int   b0   = blockIdx.y * BPG;

    if (L <= 7)
        run_all<7,  PAD>(xsrc, out, sCh, sW, sRed, n, d, off_eff, olen, bias, k, b0);
    else if (L <= 9)
        run_all<9,  PAD>(xsrc, out, sCh, sW, sRed, n, d, off_eff, olen, bias, k, b0);
    else
        run_all<11, PAD>(xsrc, out, sCh, sW, sRed, n, d, off_eff, olen, bias, k, b0);
}

// ---------------------------------------------------------------------------
extern "C" void kernel_launch(void* const* d_in, const int* in_sizes, int n_in,
                              void* d_out, int out_size, void* d_ws, size_t ws_size,
                              hipStream_t stream) {
    const float* x       = (const float*)d_in[0];
    const float* weights = (const float*)d_in[1];
    const float* biases  = (const float*)d_in[2];
    const int*   ch_idx  = (const int*)  d_in[3];
    const int*   dils    = (const int*)  d_in[4];
    const int*   offs    = (const int*)  d_in[5];
    const int*   olens   = (const int*)  d_in[6];
    float*       out     = (float*)d_out;

    const size_t need = (size_t)B_SZ * C_SZ * XP * sizeof(float);
    dim3 grid(K_SZ, BG);

    if (ws_size >= need) {
        float* xpad = (float*)d_ws;
        const int nfill = B_SZ * C_SZ * (XP / 4);
        pad_kernel<<<nfill / 256, 256, 0, stream>>>(x, xpad);
        rocket_main<true><<<grid, BLOCK, 0, stream>>>(xpad, weights, biases,
                                                      ch_idx, dils, offs, olens, out);
    } else {
        rocket_main<false><<<grid, BLOCK, 0, stream>>>(x, weights, biases,
                                                       ch_idx, dils, offs, olens, out);
    }
}

// Round 3
// 1095.220 us; speedup vs baseline: 4.1485x; 2.8105x over previous
//
#include <hip/hip_runtime.h>
#include <math.h>

// Problem constants (fixed by the reference setup)
#define B_SZ   64
#define C_SZ   12
#define T_SZ   2048
#define K_SZ   2048
#define LMAX   11
#define CMAX   11     // C-1
#define PL_PAD 1024
#define XP     8192   // padded row length (max gather pos ~7504 < 8192)
#define A_PARAM 7.0f

#define R      8      // outputs per thread item (dilation-strided register tile)
#define NW     8      // waves per block in main kernel
#define BLOCK_MAIN (NW * 64)

// ---------------------------------------------------------------------------
// Transpose + pad: xT[c][tp][b] = x[b][c][tp - PL] (0 outside). lane = b, so
// writes are perfectly coalesced 256B; reads are strided but L1-reused 16x.
__global__ __launch_bounds__(256) void tpad_kernel(const float* __restrict__ x,
                                                   float* __restrict__ xT) {
    const int c    = blockIdx.x;
    const int lane = threadIdx.x & 63;
    const int wid  = threadIdx.x >> 6;
    const int tp0  = blockIdx.y * 128 + wid * 32;
    const float* xrow = x + ((size_t)lane * C_SZ + c) * T_SZ;
    float* dst = xT + (size_t)c * XP * 64 + lane;
    #pragma unroll 4
    for (int i = 0; i < 32; ++i) {
        const int tp = tp0 + i;
        const int t  = tp - PL_PAD;
        const float v = ((unsigned)t < (unsigned)T_SZ) ? xrow[t] : 0.0f;
        dst[(size_t)tp * 64] = v;
    }
}

// ---------------------------------------------------------------------------
template<int LC>
__device__ __forceinline__ void conv_items(
    const float* __restrict__ xT,
    const int*   __restrict__ sCh,
    const float  (* __restrict__ sW)[LMAX],
    int n, int d, int nitems, int off, int olen, float bias,
    int lane, int wid, float& psum, float& pmax)
{
    constexpr int NV = R + LC - 1;
    for (int it = wid; it < nitems; it += NW) {
        const int q  = it % d;
        const int j0 = (it / d) * R;
        const int tq = q + j0 * d;            // first output t of this item
        if (tq >= T_SZ) continue;
        const int base = off + tq;            // padded coordinates (>=0)

        float y[R];
        #pragma unroll
        for (int r = 0; r < R; ++r) y[r] = bias;

        for (int c = 0; c < n; ++c) {
            const float* p = xT + (size_t)((sCh[c] * XP + base) * 64) + lane;
            float v[NV];
            #pragma unroll
            for (int i = 0; i < NV; ++i) v[i] = p[i * d * 64];
            #pragma unroll
            for (int l = 0; l < LC; ++l) {
                const float wl = sW[c][l];
                #pragma unroll
                for (int r = 0; r < R; ++r)
                    y[r] = fmaf(wl, v[l + r], y[r]);
            }
        }
        #pragma unroll
        for (int r = 0; r < R; ++r) {
            const int t = tq + r * d;
            if (t < olen) {                   // wave-uniform branch
                psum += 1.0f / (1.0f + __expf(3.0f - A_PARAM * y[r]));
                pmax  = fmaxf(pmax, y[r]);
            }
        }
    }
}

__global__ __launch_bounds__(BLOCK_MAIN, 8) void rocket_tr(
    const float* __restrict__ xT,       // (C, XP, 64)
    const float* __restrict__ weights,  // (K, CMAX, LMAX)
    const float* __restrict__ biases,
    const int*   __restrict__ ch_idx,   // (K, CMAX)
    const int*   __restrict__ dils,
    const int*   __restrict__ offs,
    const int*   __restrict__ olens,
    float*       __restrict__ out)      // (B, 2K)
{
    __shared__ float sW[CMAX][LMAX];
    __shared__ int   sCh[CMAX];
    __shared__ int   sMeta[2];
    __shared__ float sP[NW][64];
    __shared__ float sM[NW][64];

    const int k   = blockIdx.x;
    const int tid = threadIdx.x;

    if (tid < CMAX * LMAX)
        sW[tid / LMAX][tid % LMAX] = weights[(size_t)k * (CMAX * LMAX) + tid];
    if (tid < CMAX)
        sCh[tid] = ch_idx[(size_t)k * CMAX + tid];
    __syncthreads();

    if (tid == 0) {
        // Effective channel/tap counts (zero-padded rows/taps contribute 0).
        int n = 0, L = 0;
        for (int c = 0; c < CMAX; ++c) {
            bool nz = false;
            for (int l = 0; l < LMAX; ++l) {
                if (sW[c][l] != 0.0f) { nz = true; if (l + 1 > L) L = l + 1; }
            }
            if (nz) n = c + 1;
        }
        sMeta[0] = n; sMeta[1] = L;
    }
    __syncthreads();

    const int   n    = sMeta[0];
    const int   L    = sMeta[1];
    const int   d    = dils[k];
    const int   off  = offs[k];          // already includes left pad
    const int   olen = olens[k];
    const float bias = biases[k];
    const int   lane = tid & 63;
    const int   wid  = tid >> 6;

    const int nj     = (T_SZ + d - 1) / d;
    const int njblk  = (nj + R - 1) / R;
    const int nitems = d * njblk;

    float psum = 0.0f;
    float pmax = -INFINITY;

    if (L <= 7)
        conv_items<7 >(xT, sCh, sW, n, d, nitems, off, olen, bias, lane, wid, psum, pmax);
    else if (L <= 9)
        conv_items<9 >(xT, sCh, sW, n, d, nitems, off, olen, bias, lane, wid, psum, pmax);
    else
        conv_items<11>(xT, sCh, sW, n, d, nitems, off, olen, bias, lane, wid, psum, pmax);

    sP[wid][lane] = psum;
    sM[wid][lane] = pmax;
    __syncthreads();

    if (tid < 64) {
        float s = 0.0f, m = -INFINITY;
        #pragma unroll
        for (int w = 0; w < NW; ++w) {
            s += sP[w][tid];
            m  = fmaxf(m, sM[w][tid]);
        }
        const float inv_olen = 1.0f / (float)olen;
        out[(size_t)tid * (2 * K_SZ) + 2 * k]     = s * inv_olen;
        out[(size_t)tid * (2 * K_SZ) + 2 * k + 1] = m;
    }
}

// ---------------------------------------------------------------------------
// Fallback (ws too small): simple checked-gather kernel, known correct.
__global__ __launch_bounds__(256) void rocket_fallback(
    const float* __restrict__ x,
    const float* __restrict__ weights,
    const float* __restrict__ biases,
    const int*   __restrict__ ch_idx,
    const int*   __restrict__ dils,
    const int*   __restrict__ offs,
    const int*   __restrict__ olens,
    float*       __restrict__ out)
{
    __shared__ float sW[CMAX][LMAX];
    __shared__ int   sCh[CMAX];
    __shared__ float sRed[2][4];

    const int k   = blockIdx.x;
    const int tid = threadIdx.x;

    if (tid < CMAX * LMAX)
        sW[tid / LMAX][tid % LMAX] = weights[(size_t)k * (CMAX * LMAX) + tid];
    if (tid < CMAX)
        sCh[tid] = ch_idx[(size_t)k * CMAX + tid];
    __syncthreads();

    const int   d    = dils[k];
    const int   off  = offs[k] - PL_PAD;
    const int   olen = olens[k];
    const float bias = biases[k];
    const int   lane = tid & 63;
    const int   wid  = tid >> 6;

    for (int b = blockIdx.y; b < B_SZ; b += gridDim.y) {
        float psum = 0.0f, pmax = -INFINITY;
        for (int t = tid; t < T_SZ; t += 256) {
            float y = bias;
            for (int c = 0; c < CMAX; ++c) {
                const float* xb = x + ((size_t)b * C_SZ + sCh[c]) * T_SZ;
                int pos = off + t;
                for (int l = 0; l < LMAX; ++l) {
                    const float xv = ((unsigned)pos < (unsigned)T_SZ) ? xb[pos] : 0.0f;
                    y = fmaf(sW[c][l], xv, y);
                    pos += d;
                }
            }
            if (t < olen) {
                psum += 1.0f / (1.0f + __expf(3.0f - A_PARAM * y));
                pmax = fmaxf(pmax, y);
            }
        }
        for (int o = 32; o > 0; o >>= 1) {
            psum += __shfl_down(psum, o, 64);
            pmax  = fmaxf(pmax, __shfl_down(pmax, o, 64));
        }
        if (lane == 0) { sRed[0][wid] = psum; sRed[1][wid] = pmax; }
        __syncthreads();
        if (tid == 0) {
            const float s = sRed[0][0] + sRed[0][1] + sRed[0][2] + sRed[0][3];
            const float m = fmaxf(fmaxf(sRed[1][0], sRed[1][1]),
                                  fmaxf(sRed[1][2], sRed[1][3]));
            out[(size_t)b * (2 * K_SZ) + 2 * k]     = s / (float)olen;
            out[(size_t)b * (2 * K_SZ) + 2 * k + 1] = m;
        }
        __syncthreads();
    }
}

// ---------------------------------------------------------------------------
extern "C" void kernel_launch(void* const* d_in, const int* in_sizes, int n_in,
                              void* d_out, int out_size, void* d_ws, size_t ws_size,
                              hipStream_t stream) {
    const float* x       = (const float*)d_in[0];
    const float* weights = (const float*)d_in[1];
    const float* biases  = (const float*)d_in[2];
    const int*   ch_idx  = (const int*)  d_in[3];
    const int*   dils    = (const int*)  d_in[4];
    const int*   offs    = (const int*)  d_in[5];
    const int*   olens   = (const int*)  d_in[6];
    float*       out     = (float*)d_out;

    const size_t need = (size_t)C_SZ * XP * 64 * sizeof(float);   // 25.2 MB

    if (ws_size >= need) {
        float* xT = (float*)d_ws;
        dim3 tgrid(C_SZ, XP / 128);
        tpad_kernel<<<tgrid, 256, 0, stream>>>(x, xT);
        rocket_tr<<<K_SZ, BLOCK_MAIN, 0, stream>>>(xT, weights, biases, ch_idx,
                                                   dils, offs, olens, out);
    } else {
        dim3 grid(K_SZ, 16);
        rocket_fallback<<<grid, 256, 0, stream>>>(x, weights, biases, ch_idx,
                                                  dils, offs, olens, out);
    }
}